// Round 1
// baseline (415.127 us; speedup 1.0000x reference)
//
#include <hip/hip_runtime.h>
#include <math.h>

#define B_  4
#define L_  32768
#define DI  20
#define NS  10
#define RK  5
#define NC  512     // chunks per batch
#define CL  64      // chunk length; NC*CL == L_

// workspace float offsets
#define OFF_DELTA 0u
#define OFF_U     2621440u
#define OFF_BC    5242880u
#define OFF_RLOC  7864320u
#define OFF_RIN   8273920u
#define OFF_SUM   8683520u
#define OFF_CUM   8724480u
#define OFF_TOT   8765440u

// ---------------- Kernel A: pointwise preprocessing ----------------
// per timestep: h0 = x@w_in[:, :20] + b_in; conv3 causal; silu;
// xp = u@w_x + b_x;  delta = softmax(xp[:5]@w_dt + b_dt)
// stores: delta[b][d][l], u[b][d][l], bc[b][l][0:10]=B, [10:20]=C
__global__ __launch_bounds__(256) void kA(
    const float* __restrict__ x, const float* __restrict__ w_in,
    const float* __restrict__ b_in, const float* __restrict__ conv_k,
    const float* __restrict__ conv_b, const float* __restrict__ w_x,
    const float* __restrict__ b_x, const float* __restrict__ w_dt,
    const float* __restrict__ b_dt,
    float* __restrict__ delta_ws, float* __restrict__ u_ws,
    float* __restrict__ bc_ws)
{
    __shared__ float hs[258][21];      // padded leading dim -> no bank conflicts
    __shared__ float win_s[400];       // [i][o], first 20 cols of (20,40)
    __shared__ float ck_s[1200];       // (w,i,o)
    __shared__ float wx_s[500];        // (o,j) 20x25
    __shared__ float wdt_s[100];       // (r,d) 5x20
    __shared__ float bin_s[20], cb_s[20], bx_s[25], bdt_s[20];

    const int tid = threadIdx.x;
    const int b   = blockIdx.y;
    const int l0  = blockIdx.x * 256;

    for (int i = tid; i < 400;  i += 256) win_s[i] = w_in[(i/20)*40 + (i%20)];
    for (int i = tid; i < 1200; i += 256) ck_s[i]  = conv_k[i];
    for (int i = tid; i < 500;  i += 256) wx_s[i]  = w_x[i];
    for (int i = tid; i < 100;  i += 256) wdt_s[i] = w_dt[i];
    if (tid < 20) { bin_s[tid] = b_in[tid]; cb_s[tid] = conv_b[tid]; bdt_s[tid] = b_dt[tid]; }
    if (tid < 25) bx_s[tid] = b_x[tid];

    // load x rows for l in [l0-2, l0+256); l<0 -> 0 (conv zero-pads h)
    for (int idx = tid; idx < 258*20; idx += 256) {
        int p = idx / 20, i = idx - p*20;
        int l = l0 - 2 + p;
        hs[p][i] = (l >= 0) ? x[((size_t)b*L_ + l)*DI + i] : 0.0f;
    }
    __syncthreads();

    // in-place: hs row p := x_row @ w_in + b_in  (rows with l<0 stay 0)
    for (int p = tid; p < 258; p += 256) {
        int l = l0 - 2 + p;
        if (l < 0) continue;
        float xr[20];
        #pragma unroll
        for (int i = 0; i < 20; i++) xr[i] = hs[p][i];
        float h0[20];
        #pragma unroll
        for (int o = 0; o < 20; o++) h0[o] = bin_s[o];
        #pragma unroll
        for (int i = 0; i < 20; i++) {
            float xv = xr[i];
            #pragma unroll
            for (int o = 0; o < 20; o++) h0[o] = fmaf(xv, win_s[i*20+o], h0[o]);
        }
        #pragma unroll
        for (int o = 0; o < 20; o++) hs[p][o] = h0[o];
    }
    __syncthreads();

    const int l = l0 + tid;
    // causal conv over hs[tid..tid+2] (== l-2..l)
    float u[20];
    #pragma unroll
    for (int o = 0; o < 20; o++) u[o] = cb_s[o];
    #pragma unroll
    for (int w = 0; w < 3; w++) {
        #pragma unroll
        for (int i = 0; i < 20; i++) {
            float hv = hs[tid + w][i];
            const float* ck = &ck_s[(w*20 + i)*20];
            #pragma unroll
            for (int o = 0; o < 20; o++) u[o] = fmaf(hv, ck[o], u[o]);
        }
    }
    // silu
    #pragma unroll
    for (int o = 0; o < 20; o++) u[o] = u[o] / (1.0f + __expf(-u[o]));

    float xp[25];
    #pragma unroll
    for (int j = 0; j < 25; j++) xp[j] = bx_s[j];
    #pragma unroll
    for (int o = 0; o < 20; o++) {
        float uv = u[o];
        #pragma unroll
        for (int j = 0; j < 25; j++) xp[j] = fmaf(uv, wx_s[o*25+j], xp[j]);
    }

    float dl[20];
    #pragma unroll
    for (int d = 0; d < 20; d++) dl[d] = bdt_s[d];
    #pragma unroll
    for (int r = 0; r < 5; r++) {
        float dv = xp[r];
        #pragma unroll
        for (int d = 0; d < 20; d++) dl[d] = fmaf(dv, wdt_s[r*20+d], dl[d]);
    }
    float m = dl[0];
    #pragma unroll
    for (int d = 1; d < 20; d++) m = fmaxf(m, dl[d]);
    float s = 0.0f;
    #pragma unroll
    for (int d = 0; d < 20; d++) { dl[d] = __expf(dl[d] - m); s += dl[d]; }
    float inv = 1.0f / s;

    #pragma unroll
    for (int d = 0; d < 20; d++) {
        size_t o = (size_t)(b*DI + d)*L_ + l;
        delta_ws[o] = dl[d] * inv;
        u_ws[o]     = u[d];
    }
    float* bcp = bc_ws + ((size_t)b*L_ + l)*20;
    ((float4*)bcp)[0] = make_float4(xp[5],  xp[6],  xp[7],  xp[8]);
    ((float4*)bcp)[1] = make_float4(xp[9],  xp[10], xp[11], xp[12]);
    ((float4*)bcp)[2] = make_float4(xp[13], xp[14], xp[15], xp[16]);
    ((float4*)bcp)[3] = make_float4(xp[17], xp[18], xp[19], xp[20]);
    ((float4*)bcp)[4] = make_float4(xp[21], xp[22], xp[23], xp[24]);
}

// ---------------- Kernel B: per-chunk local scan + delta sums ----------------
__global__ __launch_bounds__(256) void kB(
    const float* __restrict__ delta_ws, const float* __restrict__ u_ws,
    const float* __restrict__ bc_ws, const float* __restrict__ A_log,
    float* __restrict__ rloc_ws, float* __restrict__ sum_ws)
{
    const int g   = blockIdx.x*256 + threadIdx.x;     // 0..40959
    const int b   = g / (NC*DI);
    const int rem = g - b*(NC*DI);
    const int c   = rem / DI;
    const int d   = rem - c*DI;
    const int bd  = b*DI + d;

    float A_dn[NS];
    #pragma unroll
    for (int n = 0; n < NS; n++) A_dn[n] = -__expf(A_log[d*NS+n]);

    const float* dp  = delta_ws + (size_t)bd*L_ + c*CL;
    const float* up  = u_ws     + (size_t)bd*L_ + c*CL;
    const float* bcp = bc_ws + ((size_t)b*L_ + (size_t)c*CL)*20;

    float r[NS];
    #pragma unroll
    for (int n = 0; n < NS; n++) r[n] = 0.0f;
    float s = 0.0f;

    for (int t = 0; t < CL; t++) {
        float dv = dp[t], uv = up[t];
        float du = dv * uv;
        const float* bt = bcp + t*20;
        float Bv[10];
        ((float4*)Bv)[0] = *(const float4*)(bt);
        ((float4*)Bv)[1] = *(const float4*)(bt+4);
        ((float2*)(Bv+8))[0] = *(const float2*)(bt+8);
        #pragma unroll
        for (int n = 0; n < NS; n++)
            r[n] = fmaf(__expf(A_dn[n]*dv), r[n], du*Bv[n]);
        s += dv;
    }
    const size_t bdn = (size_t)bd*NS;
    #pragma unroll
    for (int n = 0; n < NS; n++) rloc_ws[(bdn+n)*NC + c] = r[n];
    sum_ws[(size_t)bd*NC + c] = s;
}

// ---------------- Kernel C: inter-chunk scan (800 sequences x NC) ----------------
__global__ __launch_bounds__(256) void kC(
    const float* __restrict__ rloc_ws, const float* __restrict__ sum_ws,
    const float* __restrict__ A_log,
    float* __restrict__ rin_ws, float* __restrict__ cum_ws, float* __restrict__ tot_ws)
{
    const int g = blockIdx.x*256 + threadIdx.x;
    if (g >= 800) return;
    const int b   = g / 200;
    const int rem = g - b*200;
    const int d   = rem / NS;
    const int n   = rem - d*NS;
    const int bd  = b*DI + d;
    const float A_dn = -__expf(A_log[d*NS+n]);
    const size_t base  = ((size_t)bd*NS + n)*NC;
    const size_t sbase = (size_t)bd*NC;
    float rin = 0.0f, cum = 0.0f;
    for (int c = 0; c < NC; c++) {
        rin_ws[base + c] = rin;
        if (n == 0) cum_ws[sbase + c] = cum;
        float sd = sum_ws[sbase + c];
        rin = fmaf(__expf(A_dn*sd), rin, rloc_ws[base + c]);
        cum += sd;
    }
    if (n == 0) tot_ws[bd] = cum;
}

// ---------------- Kernel D: final scan + damp + output ----------------
__global__ __launch_bounds__(256) void kD(
    const float* __restrict__ delta_ws, const float* __restrict__ u_ws,
    const float* __restrict__ bc_ws, const float* __restrict__ A_log,
    const float* __restrict__ D_param,
    const float* __restrict__ rin_ws, const float* __restrict__ cum_ws,
    const float* __restrict__ tot_ws, float* __restrict__ out)
{
    const int g   = blockIdx.x*256 + threadIdx.x;
    const int b   = g / (NC*DI);
    const int rem = g - b*(NC*DI);
    const int c   = rem / DI;
    const int d   = rem - c*DI;
    const int bd  = b*DI + d;

    float A_dn[NS];
    #pragma unroll
    for (int n = 0; n < NS; n++) A_dn[n] = -__expf(A_log[d*NS+n]);

    const size_t bdn = (size_t)bd*NS;
    float r[NS];
    #pragma unroll
    for (int n = 0; n < NS; n++) r[n] = rin_ws[(bdn+n)*NC + c];
    float pref = cum_ws[(size_t)bd*NC + c];
    const float Tot = tot_ws[bd];
    const float Dd  = D_param[d];

    const float* dp  = delta_ws + (size_t)bd*L_ + c*CL;
    const float* up  = u_ws     + (size_t)bd*L_ + c*CL;
    const float* bcp = bc_ws + ((size_t)b*L_ + (size_t)c*CL)*20;
    float* op = out + ((size_t)b*L_ + (size_t)c*CL)*20 + d;

    for (int t = 0; t < CL; t++) {
        float dv = dp[t], uv = up[t];
        float du = dv * uv;
        const float* bt = bcp + t*20;
        float Bv[10], Cv[10];
        ((float4*)Bv)[0] = *(const float4*)(bt);
        ((float4*)Bv)[1] = *(const float4*)(bt+4);
        ((float2*)(Bv+8))[0] = *(const float2*)(bt+8);
        ((float2*)Cv)[0] = *(const float2*)(bt+10);
        ((float4*)(Cv+2))[0] = *(const float4*)(bt+12);
        ((float4*)(Cv+6))[0] = *(const float4*)(bt+16);
        #pragma unroll
        for (int n = 0; n < NS; n++)
            r[n] = fmaf(__expf(A_dn[n]*dv), r[n], du*Bv[n]);
        pref += dv;
        float S = Tot - pref;        // suffix sum over (t, L-1]
        float acc = 0.0f;
        #pragma unroll
        for (int n = 0; n < NS; n++) {
            float G = __expf(A_dn[n]*S);
            float damp = __fdividef(G, G + 1e-12f);  // matches ref's /(dA_cumsum+1e-12)
            acc = fmaf(Cv[n]*damp, r[n], acc);
        }
        op[t*DI] = fmaf(uv, Dd, acc);
    }
}

extern "C" void kernel_launch(void* const* d_in, const int* in_sizes, int n_in,
                              void* d_out, int out_size, void* d_ws, size_t ws_size,
                              hipStream_t stream) {
    const float* x      = (const float*)d_in[0];
    const float* w_in   = (const float*)d_in[1];
    const float* b_in   = (const float*)d_in[2];
    const float* conv_k = (const float*)d_in[3];
    const float* conv_b = (const float*)d_in[4];
    const float* w_x    = (const float*)d_in[5];
    const float* b_x    = (const float*)d_in[6];
    const float* w_dt   = (const float*)d_in[7];
    const float* b_dt   = (const float*)d_in[8];
    const float* A_log  = (const float*)d_in[9];
    const float* D_par  = (const float*)d_in[10];
    float* out = (float*)d_out;
    float* ws  = (float*)d_ws;

    float* delta_ws = ws + OFF_DELTA;
    float* u_ws     = ws + OFF_U;
    float* bc_ws    = ws + OFF_BC;
    float* rloc_ws  = ws + OFF_RLOC;
    float* rin_ws   = ws + OFF_RIN;
    float* sum_ws   = ws + OFF_SUM;
    float* cum_ws   = ws + OFF_CUM;
    float* tot_ws   = ws + OFF_TOT;

    kA<<<dim3(L_/256, B_), 256, 0, stream>>>(x, w_in, b_in, conv_k, conv_b,
                                             w_x, b_x, w_dt, b_dt,
                                             delta_ws, u_ws, bc_ws);
    kB<<<(B_*NC*DI)/256, 256, 0, stream>>>(delta_ws, u_ws, bc_ws, A_log,
                                           rloc_ws, sum_ws);
    kC<<<4, 256, 0, stream>>>(rloc_ws, sum_ws, A_log, rin_ws, cum_ws, tot_ws);
    kD<<<(B_*NC*DI)/256, 256, 0, stream>>>(delta_ws, u_ws, bc_ws, A_log, D_par,
                                           rin_ws, cum_ws, tot_ws, out);
}

// Round 2
// 220.144 us; speedup vs baseline: 1.8857x; 1.8857x over previous
//
#include <hip/hip_runtime.h>
#include <math.h>

#define B_  4
#define L_  32768
#define DI  20
#define NS  10
#define RK  5
#define NC  1024    // chunks per batch
#define CL  32      // chunk length; NC*CL == L_
#define KPL (NC/64) // chunks per lane in kC = 16

// workspace float offsets (total 8,765,520 floats = 35.06 MB, same as R1)
#define OFF_DELTA 0u
#define OFF_U     2621440u
#define OFF_BC    5242880u
#define OFF_RS    7864320u   // kB writes rloc; kC overwrites with rin in place (819200)
#define OFF_SC    8683520u   // kB writes sum;  kC overwrites with cum in place (81920)
#define OFF_TOT   8765440u   // 80

// ---------------- Kernel A: pointwise preprocessing ----------------
// per timestep: h0 = x@w_in[:, :20] + b_in; conv3 causal; silu;
// xp = u@w_x + b_x;  delta = softmax(xp[:5]@w_dt + b_dt)
// stores: delta[b][d][l], u[b][d][l], bc[b][l][0:10]=B, [10:20]=C
__global__ __launch_bounds__(256) void kA(
    const float* __restrict__ x, const float* __restrict__ w_in,
    const float* __restrict__ b_in, const float* __restrict__ conv_k,
    const float* __restrict__ conv_b, const float* __restrict__ w_x,
    const float* __restrict__ b_x, const float* __restrict__ w_dt,
    const float* __restrict__ b_dt,
    float* __restrict__ delta_ws, float* __restrict__ u_ws,
    float* __restrict__ bc_ws)
{
    __shared__ float hs[258][21];      // padded leading dim -> no bank conflicts
    __shared__ float win_s[400];       // [i][o], first 20 cols of (20,40)
    __shared__ float ck_s[1200];       // (w,i,o)
    __shared__ float wx_s[500];        // (o,j) 20x25
    __shared__ float wdt_s[100];       // (r,d) 5x20
    __shared__ float bin_s[20], cb_s[20], bx_s[25], bdt_s[20];

    const int tid = threadIdx.x;
    const int b   = blockIdx.y;
    const int l0  = blockIdx.x * 256;

    for (int i = tid; i < 400;  i += 256) win_s[i] = w_in[(i/20)*40 + (i%20)];
    for (int i = tid; i < 1200; i += 256) ck_s[i]  = conv_k[i];
    for (int i = tid; i < 500;  i += 256) wx_s[i]  = w_x[i];
    for (int i = tid; i < 100;  i += 256) wdt_s[i] = w_dt[i];
    if (tid < 20) { bin_s[tid] = b_in[tid]; cb_s[tid] = conv_b[tid]; bdt_s[tid] = b_dt[tid]; }
    if (tid < 25) bx_s[tid] = b_x[tid];

    // load x rows for l in [l0-2, l0+256); l<0 -> 0 (conv zero-pads h)
    for (int idx = tid; idx < 258*20; idx += 256) {
        int p = idx / 20, i = idx - p*20;
        int l = l0 - 2 + p;
        hs[p][i] = (l >= 0) ? x[((size_t)b*L_ + l)*DI + i] : 0.0f;
    }
    __syncthreads();

    // in-place: hs row p := x_row @ w_in + b_in  (rows with l<0 stay 0)
    for (int p = tid; p < 258; p += 256) {
        int l = l0 - 2 + p;
        if (l < 0) continue;
        float xr[20];
        #pragma unroll
        for (int i = 0; i < 20; i++) xr[i] = hs[p][i];
        float h0[20];
        #pragma unroll
        for (int o = 0; o < 20; o++) h0[o] = bin_s[o];
        #pragma unroll
        for (int i = 0; i < 20; i++) {
            float xv = xr[i];
            #pragma unroll
            for (int o = 0; o < 20; o++) h0[o] = fmaf(xv, win_s[i*20+o], h0[o]);
        }
        #pragma unroll
        for (int o = 0; o < 20; o++) hs[p][o] = h0[o];
    }
    __syncthreads();

    const int l = l0 + tid;
    // causal conv over hs[tid..tid+2] (== l-2..l)
    float u[20];
    #pragma unroll
    for (int o = 0; o < 20; o++) u[o] = cb_s[o];
    #pragma unroll
    for (int w = 0; w < 3; w++) {
        #pragma unroll
        for (int i = 0; i < 20; i++) {
            float hv = hs[tid + w][i];
            const float* ck = &ck_s[(w*20 + i)*20];
            #pragma unroll
            for (int o = 0; o < 20; o++) u[o] = fmaf(hv, ck[o], u[o]);
        }
    }
    // silu
    #pragma unroll
    for (int o = 0; o < 20; o++) u[o] = u[o] / (1.0f + __expf(-u[o]));

    float xp[25];
    #pragma unroll
    for (int j = 0; j < 25; j++) xp[j] = bx_s[j];
    #pragma unroll
    for (int o = 0; o < 20; o++) {
        float uv = u[o];
        #pragma unroll
        for (int j = 0; j < 25; j++) xp[j] = fmaf(uv, wx_s[o*25+j], xp[j]);
    }

    float dl[20];
    #pragma unroll
    for (int d = 0; d < 20; d++) dl[d] = bdt_s[d];
    #pragma unroll
    for (int r = 0; r < 5; r++) {
        float dv = xp[r];
        #pragma unroll
        for (int d = 0; d < 20; d++) dl[d] = fmaf(dv, wdt_s[r*20+d], dl[d]);
    }
    float m = dl[0];
    #pragma unroll
    for (int d = 1; d < 20; d++) m = fmaxf(m, dl[d]);
    float s = 0.0f;
    #pragma unroll
    for (int d = 0; d < 20; d++) { dl[d] = __expf(dl[d] - m); s += dl[d]; }
    float inv = 1.0f / s;

    #pragma unroll
    for (int d = 0; d < 20; d++) {
        size_t o = (size_t)(b*DI + d)*L_ + l;
        delta_ws[o] = dl[d] * inv;
        u_ws[o]     = u[d];
    }
    float* bcp = bc_ws + ((size_t)b*L_ + l)*20;
    ((float4*)bcp)[0] = make_float4(xp[5],  xp[6],  xp[7],  xp[8]);
    ((float4*)bcp)[1] = make_float4(xp[9],  xp[10], xp[11], xp[12]);
    ((float4*)bcp)[2] = make_float4(xp[13], xp[14], xp[15], xp[16]);
    ((float4*)bcp)[3] = make_float4(xp[17], xp[18], xp[19], xp[20]);
    ((float4*)bcp)[4] = make_float4(xp[21], xp[22], xp[23], xp[24]);
}

// ---------------- Kernel B: per-chunk local scan + delta sums ----------------
__global__ __launch_bounds__(256) void kB(
    const float* __restrict__ delta_ws, const float* __restrict__ u_ws,
    const float* __restrict__ bc_ws, const float* __restrict__ A_log,
    float* __restrict__ rs_ws, float* __restrict__ sc_ws)
{
    const int g   = blockIdx.x*256 + threadIdx.x;     // 0..81919
    const int b   = g / (NC*DI);
    const int rem = g - b*(NC*DI);
    const int c   = rem / DI;
    const int d   = rem - c*DI;
    const int bd  = b*DI + d;

    float A_dn[NS];
    #pragma unroll
    for (int n = 0; n < NS; n++) A_dn[n] = -__expf(A_log[d*NS+n]);

    const float* dp  = delta_ws + (size_t)bd*L_ + c*CL;
    const float* up  = u_ws     + (size_t)bd*L_ + c*CL;
    const float* bcp = bc_ws + ((size_t)b*L_ + (size_t)c*CL)*20;

    float r[NS];
    #pragma unroll
    for (int n = 0; n < NS; n++) r[n] = 0.0f;
    float s = 0.0f;

    for (int t = 0; t < CL; t++) {
        float dv = dp[t], uv = up[t];
        float du = dv * uv;
        const float* bt = bcp + t*20;
        float Bv[10];
        ((float4*)Bv)[0] = *(const float4*)(bt);
        ((float4*)Bv)[1] = *(const float4*)(bt+4);
        ((float2*)(Bv+8))[0] = *(const float2*)(bt+8);
        #pragma unroll
        for (int n = 0; n < NS; n++)
            r[n] = fmaf(__expf(A_dn[n]*dv), r[n], du*Bv[n]);
        s += dv;
    }
    const size_t bdn = (size_t)bd*NS;
    #pragma unroll
    for (int n = 0; n < NS; n++) rs_ws[(bdn+n)*NC + c] = r[n];
    sc_ws[(size_t)bd*NC + c] = s;
}

// ---------------- Kernel C: inter-chunk wave-parallel scan ----------------
// One wave (64 lanes) per (b,d) pair: 80 blocks x 64 threads.
// Each lane owns KPL=16 contiguous chunks; lane-local compose of the
// linear-recurrence operators (a,b), 6-step shfl_up butterfly scan, replay.
// rin overwrites rloc in place; cum overwrites sum in place (register-held).
__global__ __launch_bounds__(64) void kC(
    float* __restrict__ rs_ws, float* __restrict__ sc_ws,
    const float* __restrict__ A_log, float* __restrict__ tot_ws)
{
    const int bd   = blockIdx.x;          // 0..79
    const int d    = bd % DI;
    const int lane = threadIdx.x;         // 0..63
    const size_t sbase = (size_t)bd*NC + lane*KPL;

    float s_loc[KPL];
    #pragma unroll
    for (int j = 0; j < KPL; j++) s_loc[j] = sc_ws[sbase + j];

    for (int n = 0; n < NS; n++) {
        const float A = -__expf(A_log[d*NS + n]);
        const size_t rbase = ((size_t)bd*NS + n)*NC + lane*KPL;
        float a[KPL], bl[KPL];
        float Ac = 1.0f, Bc = 0.0f;
        #pragma unroll
        for (int j = 0; j < KPL; j++) {
            float av = __expf(A * s_loc[j]);
            float rv = rs_ws[rbase + j];
            a[j] = av; bl[j] = rv;
            Bc = fmaf(av, Bc, rv);   // compose: apply chunk j after composite
            Ac *= av;
        }
        // inclusive wave scan of (Ac,Bc) under (a1,b1)∘(a2,b2)=(a1a2, a2b1+b2)
        #pragma unroll
        for (int off = 1; off < 64; off <<= 1) {
            float aP = __shfl_up(Ac, off);
            float bP = __shfl_up(Bc, off);
            if (lane >= off) { Bc = fmaf(Ac, bP, Bc); Ac *= aP; }
        }
        float rIn = __shfl_up(Bc, 1);     // exclusive: state entering lane's range
        if (lane == 0) rIn = 0.0f;
        float r = rIn;
        #pragma unroll
        for (int j = 0; j < KPL; j++) {
            rs_ws[rbase + j] = r;         // rin[c] = state BEFORE chunk c
            r = fmaf(a[j], r, bl[j]);
        }
    }

    // prefix sum of per-chunk delta sums -> cum (in place) + tot
    float ssum = 0.0f;
    #pragma unroll
    for (int j = 0; j < KPL; j++) ssum += s_loc[j];
    #pragma unroll
    for (int off = 1; off < 64; off <<= 1) {
        float sP = __shfl_up(ssum, off);
        if (lane >= off) ssum += sP;
    }
    float tot = __shfl(ssum, 63);
    float sIn = __shfl_up(ssum, 1);
    if (lane == 0) sIn = 0.0f;
    float cs = sIn;
    #pragma unroll
    for (int j = 0; j < KPL; j++) {
        sc_ws[sbase + j] = cs;            // cum[c] = prefix BEFORE chunk c
        cs += s_loc[j];
    }
    if (lane == 0) tot_ws[bd] = tot;
}

// ---------------- Kernel D: final scan + damp + output ----------------
__global__ __launch_bounds__(256) void kD(
    const float* __restrict__ delta_ws, const float* __restrict__ u_ws,
    const float* __restrict__ bc_ws, const float* __restrict__ A_log,
    const float* __restrict__ D_param,
    const float* __restrict__ rs_ws, const float* __restrict__ sc_ws,
    const float* __restrict__ tot_ws, float* __restrict__ out)
{
    const int g   = blockIdx.x*256 + threadIdx.x;
    const int b   = g / (NC*DI);
    const int rem = g - b*(NC*DI);
    const int c   = rem / DI;
    const int d   = rem - c*DI;
    const int bd  = b*DI + d;

    float A_dn[NS];
    #pragma unroll
    for (int n = 0; n < NS; n++) A_dn[n] = -__expf(A_log[d*NS+n]);

    const size_t bdn = (size_t)bd*NS;
    float r[NS];
    #pragma unroll
    for (int n = 0; n < NS; n++) r[n] = rs_ws[(bdn+n)*NC + c];
    float pref = sc_ws[(size_t)bd*NC + c];
    const float Tot = tot_ws[bd];
    const float Dd  = D_param[d];

    const float* dp  = delta_ws + (size_t)bd*L_ + c*CL;
    const float* up  = u_ws     + (size_t)bd*L_ + c*CL;
    const float* bcp = bc_ws + ((size_t)b*L_ + (size_t)c*CL)*20;
    float* op = out + ((size_t)b*L_ + (size_t)c*CL)*20 + d;

    for (int t = 0; t < CL; t++) {
        float dv = dp[t], uv = up[t];
        float du = dv * uv;
        const float* bt = bcp + t*20;
        float Bv[10], Cv[10];
        ((float4*)Bv)[0] = *(const float4*)(bt);
        ((float4*)Bv)[1] = *(const float4*)(bt+4);
        ((float2*)(Bv+8))[0] = *(const float2*)(bt+8);
        ((float2*)Cv)[0] = *(const float2*)(bt+10);
        ((float4*)(Cv+2))[0] = *(const float4*)(bt+12);
        ((float4*)(Cv+6))[0] = *(const float4*)(bt+16);
        #pragma unroll
        for (int n = 0; n < NS; n++)
            r[n] = fmaf(__expf(A_dn[n]*dv), r[n], du*Bv[n]);
        pref += dv;
        float S = Tot - pref;        // suffix sum over (t, L-1]
        float acc = 0.0f;
        #pragma unroll
        for (int n = 0; n < NS; n++) {
            float G = __expf(A_dn[n]*S);
            float damp = __fdividef(G, G + 1e-12f);  // matches ref's /(dA_cumsum+1e-12)
            acc = fmaf(Cv[n]*damp, r[n], acc);
        }
        op[t*DI] = fmaf(uv, Dd, acc);
    }
}

extern "C" void kernel_launch(void* const* d_in, const int* in_sizes, int n_in,
                              void* d_out, int out_size, void* d_ws, size_t ws_size,
                              hipStream_t stream) {
    const float* x      = (const float*)d_in[0];
    const float* w_in   = (const float*)d_in[1];
    const float* b_in   = (const float*)d_in[2];
    const float* conv_k = (const float*)d_in[3];
    const float* conv_b = (const float*)d_in[4];
    const float* w_x    = (const float*)d_in[5];
    const float* b_x    = (const float*)d_in[6];
    const float* w_dt   = (const float*)d_in[7];
    const float* b_dt   = (const float*)d_in[8];
    const float* A_log  = (const float*)d_in[9];
    const float* D_par  = (const float*)d_in[10];
    float* out = (float*)d_out;
    float* ws  = (float*)d_ws;

    float* delta_ws = ws + OFF_DELTA;
    float* u_ws     = ws + OFF_U;
    float* bc_ws    = ws + OFF_BC;
    float* rs_ws    = ws + OFF_RS;
    float* sc_ws    = ws + OFF_SC;
    float* tot_ws   = ws + OFF_TOT;

    kA<<<dim3(L_/256, B_), 256, 0, stream>>>(x, w_in, b_in, conv_k, conv_b,
                                             w_x, b_x, w_dt, b_dt,
                                             delta_ws, u_ws, bc_ws);
    kB<<<(B_*NC*DI)/256, 256, 0, stream>>>(delta_ws, u_ws, bc_ws, A_log,
                                           rs_ws, sc_ws);
    kC<<<B_*DI, 64, 0, stream>>>(rs_ws, sc_ws, A_log, tot_ws);
    kD<<<(B_*NC*DI)/256, 256, 0, stream>>>(delta_ws, u_ws, bc_ws, A_log, D_par,
                                           rs_ws, sc_ws, tot_ws, out);
}

// Round 3
// 158.055 us; speedup vs baseline: 2.6265x; 1.3928x over previous
//
#include <hip/hip_runtime.h>
#include <math.h>

#define B_  4
#define L_  32768
#define DI  20
#define NS  10
#define RK  5
#define TBLK 128        // timesteps per scan-block (and per kA block)
#define NCB  (L_/TBLK)  // 256 chunks per (b,d)
#define K_   8          // timesteps per lane in scan passes (16 lanes * 8 = 128)

// workspace float offsets (total 8,294,480 floats = 33.2 MB)
#define OFF_D   0u
#define OFF_U   2621440u
#define OFF_B   5242880u
#define OFF_C   6553600u
#define OFF_AP  7864320u   // per-chunk A-products  [bd][n][NCB]
#define OFF_RS  8069120u   // kB: r_end; kC overwrites with r_in (in place)
#define OFF_SC  8273920u   // kB: delta sums; kC overwrites with cum (in place)
#define OFF_TOT 8294400u   // 80

// ---------------- Kernel A: pointwise preprocessing ----------------
// 2 threads per timestep (d-halves). Block covers 128 timesteps.
// stores delta[bd][l], u[bd][l], B[bn][l], C[bn][l]
__global__ __launch_bounds__(256, 4) void kA(
    const float* __restrict__ x, const float* __restrict__ w_in,
    const float* __restrict__ b_in, const float* __restrict__ conv_k,
    const float* __restrict__ conv_b, const float* __restrict__ w_x,
    const float* __restrict__ b_x, const float* __restrict__ w_dt,
    const float* __restrict__ b_dt,
    float* __restrict__ dws, float* __restrict__ uws,
    float* __restrict__ Bws, float* __restrict__ Cws)
{
    __shared__ float xs[130][21];
    __shared__ float h2[130][21];
    __shared__ float win_s[400];   // (i,o) first 20 cols of (20,40)
    __shared__ float ck_s[1200];   // (w,i,o)
    __shared__ float wx_s[500];    // (o,j)
    __shared__ float wdt_s[100];   // (r,d)
    __shared__ float bin_s[20], cb_s[20], bx_s[25], bdt_s[20];

    const int tid = threadIdx.x;
    const int b   = blockIdx.y;
    const int l0  = blockIdx.x * TBLK;

    for (int i = tid; i < 400;  i += 256) win_s[i] = w_in[(i/20)*40 + (i%20)];
    for (int i = tid; i < 1200; i += 256) ck_s[i]  = conv_k[i];
    for (int i = tid; i < 500;  i += 256) wx_s[i]  = w_x[i];
    for (int i = tid; i < 100;  i += 256) wdt_s[i] = w_dt[i];
    if (tid < 20) { bin_s[tid] = b_in[tid]; cb_s[tid] = conv_b[tid]; bdt_s[tid] = b_dt[tid]; }
    if (tid < 25) bx_s[tid] = b_x[tid];

    // x rows for l in [l0-2, l0+128)
    for (int idx = tid; idx < 130*20; idx += 256) {
        int p = idx / 20, i = idx - p*20;
        int l = l0 - 2 + p;
        xs[p][i] = (l >= 0) ? x[((size_t)b*L_ + l)*DI + i] : 0.0f;
    }
    __syncthreads();

    // phase1: h2 = x @ w_in + b_in ; 260 tasks = 130 rows x 2 halves
    for (int tau = tid; tau < 260; tau += 256) {
        int p = tau >> 1, hf2 = tau & 1, ob2 = hf2*10;
        int l = l0 - 2 + p;
        float acc[10];
        if (l < 0) {
            #pragma unroll
            for (int o = 0; o < 10; o++) acc[o] = 0.0f;
        } else {
            #pragma unroll
            for (int o = 0; o < 10; o++) acc[o] = bin_s[ob2 + o];
            #pragma unroll
            for (int i = 0; i < 20; i++) {
                float xv = xs[p][i];
                #pragma unroll
                for (int o = 0; o < 10; o++) acc[o] = fmaf(xv, win_s[i*20 + ob2 + o], acc[o]);
            }
        }
        #pragma unroll
        for (int o = 0; o < 10; o++) h2[p][ob2 + o] = acc[o];
    }
    __syncthreads();

    const int tl = tid >> 1, hf = tid & 1, ob = hf*10;
    const int l  = l0 + tl;

    // conv3 causal + silu (own 10 outputs)
    float u10[10];
    #pragma unroll
    for (int o = 0; o < 10; o++) u10[o] = cb_s[ob + o];
    #pragma unroll
    for (int w = 0; w < 3; w++) {
        #pragma unroll
        for (int i = 0; i < 20; i++) {
            float hv = h2[tl + w][i];
            const float* ck = &ck_s[(w*20 + i)*20 + ob];
            #pragma unroll
            for (int o = 0; o < 10; o++) u10[o] = fmaf(hv, ck[o], u10[o]);
        }
    }
    #pragma unroll
    for (int o = 0; o < 10; o++) u10[o] = u10[o] / (1.0f + __expf(-u10[o]));

    // xp = u @ w_x + b_x  (partial over own half, pair-reduce via shfl_xor)
    float xp[25];
    #pragma unroll
    for (int j = 0; j < 25; j++) xp[j] = hf ? 0.0f : bx_s[j];
    #pragma unroll
    for (int o = 0; o < 10; o++) {
        float uv = u10[o];
        #pragma unroll
        for (int j = 0; j < 25; j++) xp[j] = fmaf(uv, wx_s[(ob + o)*25 + j], xp[j]);
    }
    #pragma unroll
    for (int j = 0; j < 25; j++) xp[j] += __shfl_xor(xp[j], 1);

    // delta = softmax(xp[:5] @ w_dt + b_dt) -- own 10 d's, pair-reduce max/sum
    float dl[10];
    #pragma unroll
    for (int d = 0; d < 10; d++) dl[d] = bdt_s[ob + d];
    #pragma unroll
    for (int r = 0; r < 5; r++) {
        float dv = xp[r];
        #pragma unroll
        for (int d = 0; d < 10; d++) dl[d] = fmaf(dv, wdt_s[r*20 + ob + d], dl[d]);
    }
    float m = dl[0];
    #pragma unroll
    for (int d = 1; d < 10; d++) m = fmaxf(m, dl[d]);
    m = fmaxf(m, __shfl_xor(m, 1));
    float s = 0.0f;
    #pragma unroll
    for (int d = 0; d < 10; d++) { dl[d] = __expf(dl[d] - m); s += dl[d]; }
    s += __shfl_xor(s, 1);
    float inv = 1.0f / s;

    #pragma unroll
    for (int d = 0; d < 10; d++) {
        size_t o = (size_t)(b*DI + ob + d)*L_ + l;
        dws[o] = dl[d] * inv;
        uws[o] = u10[d];
    }
    if (hf == 0) {
        #pragma unroll
        for (int n = 0; n < NS; n++) Bws[(size_t)(b*NS + n)*L_ + l] = xp[5 + n];
    } else {
        #pragma unroll
        for (int n = 0; n < NS; n++) Cws[(size_t)(b*NS + n)*L_ + l] = xp[15 + n];
    }
}

// ---------------- Kernel B: chunk summaries via 16-lane scans ----------------
// block = 320 threads = 20 d x 16 lanes; covers 128 t for all d of one b.
__global__ __launch_bounds__(320, 4) void kB2(
    const float* __restrict__ dws, const float* __restrict__ uws,
    const float* __restrict__ Bws, const float* __restrict__ A_log,
    float* __restrict__ ap_ws, float* __restrict__ rs_ws, float* __restrict__ sc_ws)
{
    const int tid = threadIdx.x;
    const int d   = tid >> 4;
    const int s   = tid & 15;
    const int b   = blockIdx.y;
    const int blk = blockIdx.x;
    const int bd  = b*DI + d;
    const size_t t0 = (size_t)blk*TBLK + s*K_;

    float d8[8], u8[8], du8[8];
    { const float* p = dws + (size_t)bd*L_ + t0;
      *(float4*)(d8)   = *(const float4*)(p);
      *(float4*)(d8+4) = *(const float4*)(p+4); }
    { const float* p = uws + (size_t)bd*L_ + t0;
      *(float4*)(u8)   = *(const float4*)(p);
      *(float4*)(u8+4) = *(const float4*)(p+4); }
    #pragma unroll
    for (int j = 0; j < 8; j++) du8[j] = d8[j]*u8[j];

    // per-chunk delta sum
    float ssum = 0.0f;
    #pragma unroll
    for (int j = 0; j < 8; j++) ssum += d8[j];
    #pragma unroll
    for (int off = 1; off < 16; off <<= 1) ssum += __shfl_xor(ssum, off, 16);
    if (s == 0) sc_ws[(size_t)bd*NCB + blk] = ssum;

    #pragma unroll 1
    for (int n = 0; n < NS; n++) {
        const float A = -__expf(A_log[d*NS + n]);
        const float* Bp = Bws + (size_t)(b*NS + n)*L_ + t0;
        float B8[8];
        *(float4*)(B8)   = *(const float4*)(Bp);
        *(float4*)(B8+4) = *(const float4*)(Bp+4);
        float Ac = 1.0f, Bc = 0.0f;
        #pragma unroll
        for (int j = 0; j < 8; j++) {
            float a = __expf(A*d8[j]);
            Bc = fmaf(a, Bc, du8[j]*B8[j]);
            Ac *= a;
        }
        #pragma unroll
        for (int off = 1; off < 16; off <<= 1) {
            float aP = __shfl_up(Ac, off, 16);
            float bP = __shfl_up(Bc, off, 16);
            if (s >= off) { Bc = fmaf(Ac, bP, Bc); Ac *= aP; }
        }
        if (s == 15) {
            size_t o = ((size_t)bd*NS + n)*NCB + blk;
            ap_ws[o] = Ac;
            rs_ws[o] = Bc;
        }
    }
}

// ---------------- Kernel C: inter-chunk scan (one wave per (b,d)) ----------------
__global__ __launch_bounds__(64) void kC2(
    const float* __restrict__ ap_ws, float* __restrict__ rs_ws,
    float* __restrict__ sc_ws, float* __restrict__ tot_ws)
{
    const int bd   = blockIdx.x;
    const int lane = threadIdx.x;
    const size_t sb = (size_t)bd*NCB + lane*4;

    float4 sv = *(const float4*)(sc_ws + sb);
    float l1 = sv.x, l2 = l1 + sv.y, l3 = l2 + sv.z, l4 = l3 + sv.w;
    float inc = l4;
    #pragma unroll
    for (int off = 1; off < 64; off <<= 1) {
        float t = __shfl_up(inc, off);
        if (lane >= off) inc += t;
    }
    float ex = __shfl_up(inc, 1);
    if (lane == 0) ex = 0.0f;
    *(float4*)(sc_ws + sb) = make_float4(ex, ex + l1, ex + l2, ex + l3);
    if (lane == 63) tot_ws[bd] = inc;

    #pragma unroll 1
    for (int n = 0; n < NS; n++) {
        const size_t base = ((size_t)bd*NS + n)*NCB + lane*4;
        float4 av = *(const float4*)(ap_ws + base);
        float4 rv = *(const float4*)(rs_ws + base);
        float Ac = av.x, Bc = rv.x;
        Bc = fmaf(av.y, Bc, rv.y); Ac *= av.y;
        Bc = fmaf(av.z, Bc, rv.z); Ac *= av.z;
        Bc = fmaf(av.w, Bc, rv.w); Ac *= av.w;
        #pragma unroll
        for (int off = 1; off < 64; off <<= 1) {
            float aP = __shfl_up(Ac, off);
            float bP = __shfl_up(Bc, off);
            if (lane >= off) { Bc = fmaf(Ac, bP, Bc); Ac *= aP; }
        }
        float pB = __shfl_up(Bc, 1);
        if (lane == 0) pB = 0.0f;
        float r  = pB;                 // initial state is 0
        float o0 = r; r = fmaf(av.x, r, rv.x);
        float o1 = r; r = fmaf(av.y, r, rv.y);
        float o2 = r; r = fmaf(av.z, r, rv.z);
        float o3 = r;
        *(float4*)(rs_ws + base) = make_float4(o0, o1, o2, o3);
    }
}

// ---------------- Kernel D: final scans + damp + y (LDS transpose out) ----------------
__global__ __launch_bounds__(320, 4) void kD2(
    const float* __restrict__ dws, const float* __restrict__ uws,
    const float* __restrict__ Bws, const float* __restrict__ Cws,
    const float* __restrict__ A_log, const float* __restrict__ D_param,
    const float* __restrict__ rs_ws, const float* __restrict__ sc_ws,
    const float* __restrict__ tot_ws, float* __restrict__ out)
{
    __shared__ float yl[TBLK][21];
    const int tid = threadIdx.x;
    const int d   = tid >> 4;
    const int s   = tid & 15;
    const int b   = blockIdx.y;
    const int blk = blockIdx.x;
    const int bd  = b*DI + d;
    const size_t t0 = (size_t)blk*TBLK + s*K_;

    float d8[8], u8[8], du8[8];
    { const float* p = dws + (size_t)bd*L_ + t0;
      *(float4*)(d8)   = *(const float4*)(p);
      *(float4*)(d8+4) = *(const float4*)(p+4); }
    { const float* p = uws + (size_t)bd*L_ + t0;
      *(float4*)(u8)   = *(const float4*)(p);
      *(float4*)(u8+4) = *(const float4*)(p+4); }
    #pragma unroll
    for (int j = 0; j < 8; j++) du8[j] = d8[j]*u8[j];

    // inclusive local delta prefix + 16-lane exclusive prefix of lane sums
    float lp[8];
    { float run = 0.0f;
      #pragma unroll
      for (int j = 0; j < 8; j++) { run += d8[j]; lp[j] = run; } }
    float inc = lp[7];
    #pragma unroll
    for (int off = 1; off < 16; off <<= 1) {
        float t = __shfl_up(inc, off, 16);
        if (s >= off) inc += t;
    }
    float ex = __shfl_up(inc, 1, 16);
    if (s == 0) ex = 0.0f;
    const float base = sc_ws[(size_t)bd*NCB + blk] + ex;  // prefix before this lane
    const float Tot  = tot_ws[bd];

    float yacc[8];
    #pragma unroll
    for (int j = 0; j < 8; j++) yacc[j] = 0.0f;

    #pragma unroll 1
    for (int n = 0; n < NS; n++) {
        const float A = -__expf(A_log[d*NS + n]);
        const float* Bp = Bws + (size_t)(b*NS + n)*L_ + t0;
        const float* Cp = Cws + (size_t)(b*NS + n)*L_ + t0;
        float B8[8], C8[8], a8[8], b8[8];
        *(float4*)(B8)   = *(const float4*)(Bp);
        *(float4*)(B8+4) = *(const float4*)(Bp+4);
        *(float4*)(C8)   = *(const float4*)(Cp);
        *(float4*)(C8+4) = *(const float4*)(Cp+4);
        #pragma unroll
        for (int j = 0; j < 8; j++) {
            a8[j] = __expf(A*d8[j]);
            b8[j] = du8[j]*B8[j];
        }
        float Ac = 1.0f, Bc = 0.0f;
        #pragma unroll
        for (int j = 0; j < 8; j++) { Bc = fmaf(a8[j], Bc, b8[j]); Ac *= a8[j]; }
        #pragma unroll
        for (int off = 1; off < 16; off <<= 1) {
            float aP = __shfl_up(Ac, off, 16);
            float bP = __shfl_up(Bc, off, 16);
            if (s >= off) { Bc = fmaf(Ac, bP, Bc); Ac *= aP; }
        }
        float pA = __shfl_up(Ac, 1, 16);
        float pB = __shfl_up(Bc, 1, 16);
        if (s == 0) { pA = 1.0f; pB = 0.0f; }
        float r = fmaf(pA, rs_ws[((size_t)bd*NS + n)*NCB + blk], pB);

        // damp chain: G[j] = exp(A*(Tot - pref_j)); G[j] = G[j+1]*a8[j+1]
        float G[8];
        G[7] = __expf(A*(Tot - (base + lp[7])));
        #pragma unroll
        for (int j = 6; j >= 0; j--) G[j] = G[j+1]*a8[j+1];
        #pragma unroll
        for (int j = 0; j < 8; j++) {
            r = fmaf(a8[j], r, b8[j]);
            float damp = G[j] / (G[j] + 1e-12f);
            yacc[j] = fmaf(C8[j]*damp, r, yacc[j]);
        }
    }

    const float Dd = D_param[d];
    #pragma unroll
    for (int j = 0; j < 8; j++) yl[s*K_ + j][d] = fmaf(u8[j], Dd, yacc[j]);
    __syncthreads();

    // cooperative coalesced float4 store of the [128][20] tile
    float4* ob = (float4*)(out + ((size_t)b*L_ + (size_t)blk*TBLK)*DI);
    for (int i = tid; i < TBLK*DI/4; i += 320) {
        int t = i / 5, q = (i - t*5)*4;
        ob[i] = make_float4(yl[t][q], yl[t][q+1], yl[t][q+2], yl[t][q+3]);
    }
}

extern "C" void kernel_launch(void* const* d_in, const int* in_sizes, int n_in,
                              void* d_out, int out_size, void* d_ws, size_t ws_size,
                              hipStream_t stream) {
    const float* x      = (const float*)d_in[0];
    const float* w_in   = (const float*)d_in[1];
    const float* b_in   = (const float*)d_in[2];
    const float* conv_k = (const float*)d_in[3];
    const float* conv_b = (const float*)d_in[4];
    const float* w_x    = (const float*)d_in[5];
    const float* b_x    = (const float*)d_in[6];
    const float* w_dt   = (const float*)d_in[7];
    const float* b_dt   = (const float*)d_in[8];
    const float* A_log  = (const float*)d_in[9];
    const float* D_par  = (const float*)d_in[10];
    float* out = (float*)d_out;
    float* ws  = (float*)d_ws;

    float* dws    = ws + OFF_D;
    float* uws    = ws + OFF_U;
    float* Bws    = ws + OFF_B;
    float* Cws    = ws + OFF_C;
    float* ap_ws  = ws + OFF_AP;
    float* rs_ws  = ws + OFF_RS;
    float* sc_ws  = ws + OFF_SC;
    float* tot_ws = ws + OFF_TOT;

    kA<<<dim3(L_/TBLK, B_), 256, 0, stream>>>(x, w_in, b_in, conv_k, conv_b,
                                              w_x, b_x, w_dt, b_dt,
                                              dws, uws, Bws, Cws);
    kB2<<<dim3(NCB, B_), 320, 0, stream>>>(dws, uws, Bws, A_log,
                                           ap_ws, rs_ws, sc_ws);
    kC2<<<B_*DI, 64, 0, stream>>>(ap_ws, rs_ws, sc_ws, tot_ws);
    kD2<<<dim3(NCB, B_), 320, 0, stream>>>(dws, uws, Bws, Cws, A_log, D_par,
                                           rs_ws, sc_ws, tot_ws, out);
}